// Round 2
// baseline (411.414 us; speedup 1.0000x reference)
//
#include <hip/hip_runtime.h>
#include <hip/hip_bf16.h>

#define B_SZ 4
#define NHEADS 16
#define T_SZ 2048
#define DE 1024
#define DH 64
#define BH (B_SZ*NHEADS)
#define SCL 0.18033688011112042f  /* 0.125 * log2(e) */

typedef __attribute__((ext_vector_type(8))) short short8;   // 8 bf16 = 4 VGPRs
typedef __attribute__((ext_vector_type(4))) float float4v;

__device__ __forceinline__ short f2bf(float f) {
    __hip_bfloat16 h = __float2bfloat16(f);
    return *reinterpret_cast<short*>(&h);
}
__device__ __forceinline__ float4v zero4() {
    float4v z = {0.f, 0.f, 0.f, 0.f};
    return z;
}

// ---- transpose+downcast: fp32 src[R][C] -> bf16 dst[C][R], batched over z ---
__global__ __launch_bounds__(256) void transpose_k(const float* __restrict__ src,
                                                   short* __restrict__ dst,
                                                   int R, int C) {
    __shared__ __align__(16) short tile[64 * 65];
    int c0 = blockIdx.x * 64, r0 = blockIdx.y * 64;
    src += (size_t)blockIdx.z * R * C;
    dst += (size_t)blockIdx.z * R * C;
    int tid = threadIdx.x;
#pragma unroll
    for (int it = 0; it < 16; ++it) {
        int idx = it * 256 + tid;
        int rr = idx >> 6, cc = idx & 63;
        tile[cc * 65 + rr] = f2bf(src[(size_t)(r0 + rr) * C + c0 + cc]);
    }
    __syncthreads();
#pragma unroll
    for (int it = 0; it < 16; ++it) {
        int idx = it * 256 + tid;
        int cc = idx >> 6, rr = idx & 63;
        dst[(size_t)(c0 + cc) * R + r0 + rr] = tile[cc * 65 + rr];
    }
}

// ---------------- QKV projection + q/k norm ---------------------------------
// XT: [b][t][d] (d contig, bf16), WT: [nh][e][d] (d contig, bf16)
// Qw,Kw: [bh][t][e] ; Vt: [bh][e][t]   (all bf16)
__global__ __launch_bounds__(256) void qkv_k(const short* __restrict__ XT,
                                             const short* __restrict__ WT,
                                             short* __restrict__ Qw,
                                             short* __restrict__ Kw,
                                             short* __restrict__ Vt) {
    __shared__ __align__(16) short ldsA[128 * 72];
    __shared__ __align__(16) short ldsB[64 * 72];
    int t0 = blockIdx.x * 128;
    int nh = blockIdx.y;           // n*16 + h
    int b  = blockIdx.z;
    int n = nh >> 4, h = nh & 15;
    int tid = threadIdx.x, wave = tid >> 6, lane = tid & 63;
    int l15 = lane & 15, quad = lane >> 4;

    const short* Arow = XT + ((size_t)b * T_SZ + t0) * DE;
    const short* Brow = WT + (size_t)nh * DH * DE;

    float4v acc[2][4];
#pragma unroll
    for (int bd = 0; bd < 2; ++bd)
#pragma unroll
        for (int j = 0; j < 4; ++j) acc[bd][j] = zero4();

    for (int k0 = 0; k0 < DE; k0 += 64) {
        __syncthreads();
#pragma unroll
        for (int it = 0; it < 4; ++it) {       // A: 128x64 = 1024 chunks of 8
            int idx = it * 256 + tid;
            int row = idx >> 3, d8 = (idx & 7) * 8;
            *(short8*)&ldsA[row * 72 + d8] =
                *(const short8*)&Arow[(size_t)row * DE + k0 + d8];
        }
#pragma unroll
        for (int it = 0; it < 2; ++it) {       // B: 64x64 = 512 chunks
            int idx = it * 256 + tid;
            int row = idx >> 3, d8 = (idx & 7) * 8;
            *(short8*)&ldsB[row * 72 + d8] =
                *(const short8*)&Brow[(size_t)row * DE + k0 + d8];
        }
        __syncthreads();
#pragma unroll
        for (int ks = 0; ks < 2; ++ks) {
            short8 a0 = *(const short8*)&ldsA[(16 * wave + l15) * 72 + ks * 32 + quad * 8];
            short8 a1 = *(const short8*)&ldsA[(64 + 16 * wave + l15) * 72 + ks * 32 + quad * 8];
#pragma unroll
            for (int j = 0; j < 4; ++j) {
                short8 bb = *(const short8*)&ldsB[(16 * j + l15) * 72 + ks * 32 + quad * 8];
                acc[0][j] = __builtin_amdgcn_mfma_f32_16x16x32_bf16(a0, bb, acc[0][j], 0, 0, 0);
                acc[1][j] = __builtin_amdgcn_mfma_f32_16x16x32_bf16(a1, bb, acc[1][j], 0, 0, 0);
            }
        }
    }

    int bh = b * NHEADS + h;
#pragma unroll
    for (int bd = 0; bd < 2; ++bd) {
        int tbase = t0 + 64 * bd + 16 * wave;
        if (n < 2) {
            float mu[4], inv[4];
#pragma unroll
            for (int r = 0; r < 4; ++r) {
                float s1 = 0.f, s2 = 0.f;
#pragma unroll
                for (int j = 0; j < 4; ++j) { float v = acc[bd][j][r]; s1 += v; s2 += v * v; }
                for (int mm = 1; mm < 16; mm <<= 1) {
                    s1 += __shfl_xor(s1, mm, 64);
                    s2 += __shfl_xor(s2, mm, 64);
                }
                mu[r] = s1 * (1.0f / 64.0f);
                float var = (s2 - 64.0f * mu[r] * mu[r]) * (1.0f / 63.0f);
                var = fmaxf(var, 0.0f);
                inv[r] = 1.0f / (sqrtf(var) + 1e-5f);
            }
            short* dst = (n == 0 ? Qw : Kw) + (size_t)bh * T_SZ * DH;
#pragma unroll
            for (int r = 0; r < 4; ++r) {
                int t = tbase + quad * 4 + r;
#pragma unroll
                for (int j = 0; j < 4; ++j) {
                    float v = (acc[bd][j][r] - mu[r]) * inv[r];
                    dst[(size_t)t * DH + 16 * j + l15] = f2bf(v);
                }
            }
        } else {
#pragma unroll
            for (int r = 0; r < 4; ++r) {
                int t = tbase + quad * 4 + r;
#pragma unroll
                for (int j = 0; j < 4; ++j) {
                    Vt[((size_t)bh * DH + 16 * j + l15) * T_SZ + t] = f2bf(acc[bd][j][r]);
                }
            }
        }
    }
}

// ---------------- flash attention -------------------------------------------
// Qw,Kw: [bh][t][e] ; Vt: [bh][e][t]  (bf16) ; out: fp32 [b][h*64+e][t]
__global__ __launch_bounds__(256) void attn_k(const short* __restrict__ Qw,
                                              const short* __restrict__ Kw,
                                              const short* __restrict__ Vt,
                                              float* __restrict__ out) {
    // 3 bf16 buffers (64x72 each) for the loop; fp32 64x68 epilogue buffer aliases them
    __shared__ __align__(16) char smem[3 * 64 * 72 * 2];
    short* ldsK = (short*)smem;
    short* ldsV = (short*)(smem + 64 * 72 * 2);       // [e][s]
    short* ldsP = (short*)(smem + 2 * 64 * 72 * 2);   // [t_local][s]
    float* ldsO = (float*)smem;                        // [e][t_local], stride 68

    int t0 = blockIdx.x * 64;
    int bh = blockIdx.y;
    int b = bh >> 4, h = bh & 15;
    int tid = threadIdx.x, wave = tid >> 6, lane = tid & 63;
    int l15 = lane & 15, quad = lane >> 4;

    const short* Qp = Qw + (size_t)bh * T_SZ * DH;
    const short* Kp = Kw + (size_t)bh * T_SZ * DH;
    const short* Vp = Vt + (size_t)bh * DH * T_SZ;

    short8 qf[2];
#pragma unroll
    for (int ks = 0; ks < 2; ++ks)
        qf[ks] = *(const short8*)&Qp[(size_t)(t0 + 16 * wave + l15) * DH + ks * 32 + quad * 8];

    float m_run[4], l_run[4];
    float4v o[4];
#pragma unroll
    for (int r = 0; r < 4; ++r) { m_run[r] = -1e30f; l_run[r] = 0.f; }
#pragma unroll
    for (int j = 0; j < 4; ++j) o[j] = zero4();

    for (int s0 = 0; s0 < T_SZ; s0 += 64) {
        __syncthreads();
#pragma unroll
        for (int it = 0; it < 2; ++it) {   // stage K [s][e] and V^T [e][s]
            int idx = it * 256 + tid;
            int row = idx >> 3, c8 = (idx & 7) * 8;
            *(short8*)&ldsK[row * 72 + c8] = *(const short8*)&Kp[(size_t)(s0 + row) * DH + c8];
            *(short8*)&ldsV[row * 72 + c8] = *(const short8*)&Vp[(size_t)row * T_SZ + s0 + c8];
        }
        __syncthreads();

        float4v s4[4];
#pragma unroll
        for (int j = 0; j < 4; ++j) {
            short8 k0 = *(const short8*)&ldsK[(16 * j + l15) * 72 + quad * 8];
            short8 k1 = *(const short8*)&ldsK[(16 * j + l15) * 72 + 32 + quad * 8];
            float4v z = zero4();
            z = __builtin_amdgcn_mfma_f32_16x16x32_bf16(qf[0], k0, z, 0, 0, 0);
            z = __builtin_amdgcn_mfma_f32_16x16x32_bf16(qf[1], k1, z, 0, 0, 0);
            s4[j] = z;
        }

        float mnew[4], alpha[4], rsum[4];
#pragma unroll
        for (int r = 0; r < 4; ++r) {
            float mx = fmaxf(fmaxf(s4[0][r], s4[1][r]), fmaxf(s4[2][r], s4[3][r]));
            for (int mm = 1; mm < 16; mm <<= 1) mx = fmaxf(mx, __shfl_xor(mx, mm, 64));
            mx *= SCL;
            float mn = fmaxf(m_run[r], mx);
            alpha[r] = exp2f(m_run[r] - mn);
            mnew[r] = mn; rsum[r] = 0.f;
        }
#pragma unroll
        for (int j = 0; j < 4; ++j) {
#pragma unroll
            for (int r = 0; r < 4; ++r) {
                float p = exp2f(s4[j][r] * SCL - mnew[r]);
                rsum[r] += p;
                ldsP[(16 * wave + quad * 4 + r) * 72 + 16 * j + l15] = f2bf(p);
            }
        }
#pragma unroll
        for (int r = 0; r < 4; ++r) {
            float s = rsum[r];
            for (int mm = 1; mm < 16; mm <<= 1) s += __shfl_xor(s, mm, 64);
            l_run[r] = l_run[r] * alpha[r] + s;
            m_run[r] = mnew[r];
        }
#pragma unroll
        for (int j = 0; j < 4; ++j)
#pragma unroll
            for (int r = 0; r < 4; ++r) o[j][r] *= alpha[r];

        __syncthreads();  // P visible to all waves

        short8 pf0 = *(const short8*)&ldsP[(16 * wave + l15) * 72 + quad * 8];
        short8 pf1 = *(const short8*)&ldsP[(16 * wave + l15) * 72 + 32 + quad * 8];
#pragma unroll
        for (int j = 0; j < 4; ++j) {
            short8 v0 = *(const short8*)&ldsV[(16 * j + l15) * 72 + quad * 8];
            short8 v1 = *(const short8*)&ldsV[(16 * j + l15) * 72 + 32 + quad * 8];
            o[j] = __builtin_amdgcn_mfma_f32_16x16x32_bf16(pf0, v0, o[j], 0, 0, 0);
            o[j] = __builtin_amdgcn_mfma_f32_16x16x32_bf16(pf1, v1, o[j], 0, 0, 0);
        }
    }

    // epilogue: O/l (fp32), transpose via LDS, coalesced float4 stores
    __syncthreads();   // loop reads of ldsK/ldsV/ldsP complete before aliasing as ldsO
    float rinv[4];
#pragma unroll
    for (int r = 0; r < 4; ++r) rinv[r] = 1.0f / l_run[r];
#pragma unroll
    for (int j = 0; j < 4; ++j)
#pragma unroll
        for (int r = 0; r < 4; ++r)
            ldsO[(16 * j + l15) * 68 + 16 * wave + quad * 4 + r] = o[j][r] * rinv[r];
    __syncthreads();
#pragma unroll
    for (int it = 0; it < 4; ++it) {
        int idx = it * 256 + tid;           // 1024 float4s = 64x64 floats
        int e = idx >> 4, t4 = (idx & 15) * 4;
        *(float4v*)&out[((size_t)(b * DE + h * DH + e)) * T_SZ + t0 + t4] =
            *(const float4v*)&ldsO[e * 68 + t4];
    }
}

extern "C" void kernel_launch(void* const* d_in, const int* in_sizes, int n_in,
                              void* d_out, int out_size, void* d_ws, size_t ws_size,
                              hipStream_t stream) {
    const float* x = (const float*)d_in[0];   // fp32 [B][D][T]
    const float* w = (const float*)d_in[1];   // fp32 [3][H][D][dh]
    float* out = (float*)d_out;               // fp32 [B][D][T]
    char* ws = (char*)d_ws;

    const size_t XT_BYTES = (size_t)B_SZ * T_SZ * DE * 2;       // 16.8 MB (bf16)
    const size_t WT_BYTES = (size_t)3 * NHEADS * DH * DE * 2;   // 6.3 MB
    const size_t QKV_BYTES = (size_t)BH * T_SZ * DH * 2;        // 16.8 MB each

    short* XT = (short*)(ws);
    short* WT = (short*)(ws + XT_BYTES);
    short* Qw = (short*)(ws + XT_BYTES + WT_BYTES);
    short* Kw = (short*)(ws + XT_BYTES + WT_BYTES + QKV_BYTES);
    short* Vt = (short*)(ws + XT_BYTES + WT_BYTES + 2 * QKV_BYTES);

    // x: per-b fp32 [D][T] -> bf16 XT [T][D]
    transpose_k<<<dim3(T_SZ / 64, DE / 64, B_SZ), 256, 0, stream>>>(x, XT, DE, T_SZ);
    // w: per-nh fp32 [D][dh] -> bf16 WT [dh][D]
    transpose_k<<<dim3(1, DE / 64, 3 * NHEADS), 256, 0, stream>>>(w, WT, DE, DH);
    qkv_k<<<dim3(T_SZ / 128, 3 * NHEADS, B_SZ), 256, 0, stream>>>(XT, WT, Qw, Kw, Vt);
    attn_k<<<dim3(T_SZ / 64, BH), 256, 0, stream>>>(Qw, Kw, Vt, out);
}

// Round 3
// 307.760 us; speedup vs baseline: 1.3368x; 1.3368x over previous
//
#include <hip/hip_runtime.h>
#include <hip/hip_bf16.h>

#define B_SZ 4
#define NHEADS 16
#define T_SZ 2048
#define DE 1024
#define DH 64
#define BH (B_SZ*NHEADS)
#define SCL 0.18033688011112042f  /* 0.125 * log2(e) */

typedef __attribute__((ext_vector_type(8))) short short8;   // 8 bf16 = 4 VGPRs
typedef __attribute__((ext_vector_type(4))) float float4v;
typedef __attribute__((ext_vector_type(2))) unsigned int uint2v;

__device__ __forceinline__ short f2bf(float f) {
    __hip_bfloat16 h = __float2bfloat16(f);
    return *reinterpret_cast<short*>(&h);
}
__device__ __forceinline__ unsigned int pack_bf2(float a, float b) {
    float2 f; f.x = a; f.y = b;
    __hip_bfloat162 h = __float22bfloat162_rn(f);
    return *reinterpret_cast<unsigned int*>(&h);
}
__device__ __forceinline__ float4v zero4() {
    float4v z = {0.f, 0.f, 0.f, 0.f};
    return z;
}

// ---- transpose+downcast: fp32 src[R][C] -> bf16 dst[C][R], batched over z ---
__global__ __launch_bounds__(256) void transpose_k(const float* __restrict__ src,
                                                   short* __restrict__ dst,
                                                   int R, int C) {
    __shared__ __align__(16) short tile[64 * 65];
    int c0 = blockIdx.x * 64, r0 = blockIdx.y * 64;
    src += (size_t)blockIdx.z * R * C;
    dst += (size_t)blockIdx.z * R * C;
    int tid = threadIdx.x;
#pragma unroll
    for (int it = 0; it < 16; ++it) {
        int idx = it * 256 + tid;
        int rr = idx >> 6, cc = idx & 63;
        tile[cc * 65 + rr] = f2bf(src[(size_t)(r0 + rr) * C + c0 + cc]);
    }
    __syncthreads();
#pragma unroll
    for (int it = 0; it < 16; ++it) {
        int idx = it * 256 + tid;
        int cc = idx >> 6, rr = idx & 63;
        dst[(size_t)(c0 + cc) * R + r0 + rr] = tile[cc * 65 + rr];
    }
}

// ---------------- QKV projection + q/k norm ---------------------------------
// XT: [b][t][d] (d contig, bf16), WT: [nh][e][d] (d contig, bf16)
// Qw (pre-scaled by SCL), Kw: [bh][t][e] ; Vt: [bh][e][t]   (all bf16)
__global__ __launch_bounds__(256) void qkv_k(const short* __restrict__ XT,
                                             const short* __restrict__ WT,
                                             short* __restrict__ Qw,
                                             short* __restrict__ Kw,
                                             short* __restrict__ Vt) {
    __shared__ __align__(16) short ldsA[128 * 72];
    __shared__ __align__(16) short ldsB[64 * 72];
    int t0 = blockIdx.x * 128;
    int nh = blockIdx.y;           // n*16 + h
    int b  = blockIdx.z;
    int n = nh >> 4, h = nh & 15;
    int tid = threadIdx.x, wave = tid >> 6, lane = tid & 63;
    int l15 = lane & 15, quad = lane >> 4;

    const short* Arow = XT + ((size_t)b * T_SZ + t0) * DE;
    const short* Brow = WT + (size_t)nh * DH * DE;

    float4v acc[2][4];
#pragma unroll
    for (int bd = 0; bd < 2; ++bd)
#pragma unroll
        for (int j = 0; j < 4; ++j) acc[bd][j] = zero4();

    for (int k0 = 0; k0 < DE; k0 += 64) {
        __syncthreads();
#pragma unroll
        for (int it = 0; it < 4; ++it) {       // A: 128x64 = 1024 chunks of 8
            int idx = it * 256 + tid;
            int row = idx >> 3, d8 = (idx & 7) * 8;
            *(short8*)&ldsA[row * 72 + d8] =
                *(const short8*)&Arow[(size_t)row * DE + k0 + d8];
        }
#pragma unroll
        for (int it = 0; it < 2; ++it) {       // B: 64x64 = 512 chunks
            int idx = it * 256 + tid;
            int row = idx >> 3, d8 = (idx & 7) * 8;
            *(short8*)&ldsB[row * 72 + d8] =
                *(const short8*)&Brow[(size_t)row * DE + k0 + d8];
        }
        __syncthreads();
#pragma unroll
        for (int ks = 0; ks < 2; ++ks) {
            short8 a0 = *(const short8*)&ldsA[(16 * wave + l15) * 72 + ks * 32 + quad * 8];
            short8 a1 = *(const short8*)&ldsA[(64 + 16 * wave + l15) * 72 + ks * 32 + quad * 8];
#pragma unroll
            for (int j = 0; j < 4; ++j) {
                short8 bb = *(const short8*)&ldsB[(16 * j + l15) * 72 + ks * 32 + quad * 8];
                acc[0][j] = __builtin_amdgcn_mfma_f32_16x16x32_bf16(a0, bb, acc[0][j], 0, 0, 0);
                acc[1][j] = __builtin_amdgcn_mfma_f32_16x16x32_bf16(a1, bb, acc[1][j], 0, 0, 0);
            }
        }
    }

    int bh = b * NHEADS + h;
#pragma unroll
    for (int bd = 0; bd < 2; ++bd) {
        int tbase = t0 + 64 * bd + 16 * wave;
        if (n < 2) {
            float oscale = (n == 0) ? SCL : 1.0f;   // fold attention scale into Q
            float mu[4], inv[4];
#pragma unroll
            for (int r = 0; r < 4; ++r) {
                float s1 = 0.f, s2 = 0.f;
#pragma unroll
                for (int j = 0; j < 4; ++j) { float v = acc[bd][j][r]; s1 += v; s2 += v * v; }
                for (int mm = 1; mm < 16; mm <<= 1) {
                    s1 += __shfl_xor(s1, mm, 64);
                    s2 += __shfl_xor(s2, mm, 64);
                }
                mu[r] = s1 * (1.0f / 64.0f);
                float var = (s2 - 64.0f * mu[r] * mu[r]) * (1.0f / 63.0f);
                var = fmaxf(var, 0.0f);
                inv[r] = oscale / (sqrtf(var) + 1e-5f);
            }
            short* dst = (n == 0 ? Qw : Kw) + (size_t)bh * T_SZ * DH;
#pragma unroll
            for (int r = 0; r < 4; ++r) {
                int t = tbase + quad * 4 + r;
#pragma unroll
                for (int j = 0; j < 4; ++j) {
                    float v = (acc[bd][j][r] - mu[r]) * inv[r];
                    dst[(size_t)t * DH + 16 * j + l15] = f2bf(v);
                }
            }
        } else {
#pragma unroll
            for (int r = 0; r < 4; ++r) {
                int t = tbase + quad * 4 + r;
#pragma unroll
                for (int j = 0; j < 4; ++j) {
                    Vt[((size_t)bh * DH + 16 * j + l15) * T_SZ + t] = f2bf(acc[bd][j][r]);
                }
            }
        }
    }
}

// ---------------- flash attention (one-pass softmax, S^T trick) --------------
// Qw (pre-scaled), Kw: [bh][t][e] ; Vt: [bh][e][t]  (bf16) ; out: fp32 [b][h*64+e][t]
// |q.k*SCL| <= 63*0.1803 = 11.4  -> exp2 can never overflow; no max subtraction.
__global__ __launch_bounds__(256) void attn_k(const short* __restrict__ Qw,
                                              const short* __restrict__ Kw,
                                              const short* __restrict__ Vt,
                                              float* __restrict__ out) {
    __shared__ __align__(16) char smem[3 * 64 * 72 * 2];
    short* ldsK = (short*)smem;                        // [s][e]
    short* ldsV = (short*)(smem + 64 * 72 * 2);        // [e][s]
    short* ldsP = (short*)(smem + 2 * 64 * 72 * 2);    // [t_local][s]
    float* ldsO = (float*)smem;                        // epilogue alias, stride 68

    int t0 = blockIdx.x * 64;
    int bh = blockIdx.y;
    int b = bh >> 4, h = bh & 15;
    int tid = threadIdx.x, wave = tid >> 6, lane = tid & 63;
    int l15 = lane & 15, quad = lane >> 4;

    const short* Qp = Qw + (size_t)bh * T_SZ * DH;
    const short* Kp = Kw + (size_t)bh * T_SZ * DH;
    const short* Vp = Vt + (size_t)bh * DH * T_SZ;

    short8 qf[2];   // B-operand fragment: lane holds Q[t=t0+16w+l15][e=ks*32+quad*8 ..+7]
#pragma unroll
    for (int ks = 0; ks < 2; ++ks)
        qf[ks] = *(const short8*)&Qp[(size_t)(t0 + 16 * wave + l15) * DH + ks * 32 + quad * 8];

    float lsum = 0.f;
    float4v o[4];
#pragma unroll
    for (int j = 0; j < 4; ++j) o[j] = zero4();

    for (int s0 = 0; s0 < T_SZ; s0 += 64) {
        __syncthreads();
#pragma unroll
        for (int it = 0; it < 2; ++it) {   // stage K [s][e] and V^T [e][s]
            int idx = it * 256 + tid;
            int row = idx >> 3, c8 = (idx & 7) * 8;
            *(short8*)&ldsK[row * 72 + c8] = *(const short8*)&Kp[(size_t)(s0 + row) * DH + c8];
            *(short8*)&ldsV[row * 72 + c8] = *(const short8*)&Vp[(size_t)row * T_SZ + s0 + c8];
        }
        __syncthreads();

        // S^T = K.Q^T : C[row=s_local][col=t_local]; 4 regs = 4 consecutive s
#pragma unroll
        for (int j = 0; j < 4; ++j) {
            short8 k0 = *(const short8*)&ldsK[(16 * j + l15) * 72 + quad * 8];
            short8 k1 = *(const short8*)&ldsK[(16 * j + l15) * 72 + 32 + quad * 8];
            float4v z = zero4();
            z = __builtin_amdgcn_mfma_f32_16x16x32_bf16(k0, qf[0], z, 0, 0, 0);
            z = __builtin_amdgcn_mfma_f32_16x16x32_bf16(k1, qf[1], z, 0, 0, 0);
            float p0 = __builtin_amdgcn_exp2f(z[0]);
            float p1 = __builtin_amdgcn_exp2f(z[1]);
            float p2 = __builtin_amdgcn_exp2f(z[2]);
            float p3 = __builtin_amdgcn_exp2f(z[3]);
            lsum += (p0 + p1) + (p2 + p3);
            uint2v u = { pack_bf2(p0, p1), pack_bf2(p2, p3) };
            // P[t=16w+l15][s = 16j + quad*4 + r] — intra-wave rows only
            *(uint2v*)&ldsP[(16 * wave + l15) * 72 + 16 * j + quad * 4] = u;
        }

        // PV: A = P (rows of this wave), B = V^T — no barrier needed (same wave)
        short8 pf0 = *(const short8*)&ldsP[(16 * wave + l15) * 72 + quad * 8];
        short8 pf1 = *(const short8*)&ldsP[(16 * wave + l15) * 72 + 32 + quad * 8];
#pragma unroll
        for (int j = 0; j < 4; ++j) {
            short8 v0 = *(const short8*)&ldsV[(16 * j + l15) * 72 + quad * 8];
            short8 v1 = *(const short8*)&ldsV[(16 * j + l15) * 72 + 32 + quad * 8];
            o[j] = __builtin_amdgcn_mfma_f32_16x16x32_bf16(pf0, v0, o[j], 0, 0, 0);
            o[j] = __builtin_amdgcn_mfma_f32_16x16x32_bf16(pf1, v1, o[j], 0, 0, 0);
        }
    }

    // final l reduction: lane holds partial sum for t = t0 + 16w + l15
    lsum += __shfl_xor(lsum, 16, 64);
    lsum += __shfl_xor(lsum, 32, 64);
    float rinv[4];
#pragma unroll
    for (int r = 0; r < 4; ++r)
        rinv[r] = 1.0f / __shfl(lsum, quad * 4 + r, 16);   // l for t = 16w + quad*4 + r

    // epilogue: O/l (fp32), transpose via LDS, coalesced float4 stores
    __syncthreads();
#pragma unroll
    for (int j = 0; j < 4; ++j)
#pragma unroll
        for (int r = 0; r < 4; ++r)
            ldsO[(16 * j + l15) * 68 + 16 * wave + quad * 4 + r] = o[j][r] * rinv[r];
    __syncthreads();
#pragma unroll
    for (int it = 0; it < 4; ++it) {
        int idx = it * 256 + tid;           // 1024 float4s = 64x64 floats
        int e = idx >> 4, t4 = (idx & 15) * 4;
        *(float4v*)&out[((size_t)(b * DE + h * DH + e)) * T_SZ + t0 + t4] =
            *(const float4v*)&ldsO[e * 68 + t4];
    }
}

extern "C" void kernel_launch(void* const* d_in, const int* in_sizes, int n_in,
                              void* d_out, int out_size, void* d_ws, size_t ws_size,
                              hipStream_t stream) {
    const float* x = (const float*)d_in[0];   // fp32 [B][D][T]
    const float* w = (const float*)d_in[1];   // fp32 [3][H][D][dh]
    float* out = (float*)d_out;               // fp32 [B][D][T]
    char* ws = (char*)d_ws;

    const size_t XT_BYTES = (size_t)B_SZ * T_SZ * DE * 2;       // 16.8 MB (bf16)
    const size_t WT_BYTES = (size_t)3 * NHEADS * DH * DE * 2;   // 6.3 MB
    const size_t QKV_BYTES = (size_t)BH * T_SZ * DH * 2;        // 16.8 MB each

    short* XT = (short*)(ws);
    short* WT = (short*)(ws + XT_BYTES);
    short* Qw = (short*)(ws + XT_BYTES + WT_BYTES);
    short* Kw = (short*)(ws + XT_BYTES + WT_BYTES + QKV_BYTES);
    short* Vt = (short*)(ws + XT_BYTES + WT_BYTES + 2 * QKV_BYTES);

    // x: per-b fp32 [D][T] -> bf16 XT [T][D]
    transpose_k<<<dim3(T_SZ / 64, DE / 64, B_SZ), 256, 0, stream>>>(x, XT, DE, T_SZ);
    // w: per-nh fp32 [D][dh] -> bf16 WT [dh][D]
    transpose_k<<<dim3(1, DE / 64, 3 * NHEADS), 256, 0, stream>>>(w, WT, DE, DH);
    qkv_k<<<dim3(T_SZ / 128, 3 * NHEADS, B_SZ), 256, 0, stream>>>(XT, WT, Qw, Kw, Vt);
    attn_k<<<dim3(T_SZ / 64, BH), 256, 0, stream>>>(Qw, Kw, Vt, out);
}

// Round 4
// 257.279 us; speedup vs baseline: 1.5991x; 1.1962x over previous
//
#include <hip/hip_runtime.h>
#include <hip/hip_bf16.h>

#define B_SZ 4
#define NHEADS 16
#define T_SZ 2048
#define DE 1024
#define DH 64
#define BH (B_SZ*NHEADS)
#define SCL 0.18033688011112042f  /* 0.125 * log2(e) */

typedef __attribute__((ext_vector_type(8))) short short8;   // 8 bf16 = 4 VGPRs
typedef __attribute__((ext_vector_type(4))) float float4v;
typedef __attribute__((ext_vector_type(2))) unsigned int uint2v;

__device__ __forceinline__ short f2bf(float f) {
    __hip_bfloat16 h = __float2bfloat16(f);
    return *reinterpret_cast<short*>(&h);
}
__device__ __forceinline__ unsigned int pack_bf2(float a, float b) {
    float2 f; f.x = a; f.y = b;
    __hip_bfloat162 h = __float22bfloat162_rn(f);
    return *reinterpret_cast<unsigned int*>(&h);
}
__device__ __forceinline__ float4v zero4() {
    float4v z = {0.f, 0.f, 0.f, 0.f};
    return z;
}

// ---- transpose+downcast: fp32 src[R][C] -> bf16 dst[C][R], batched over z ---
__global__ __launch_bounds__(256) void transpose_k(const float* __restrict__ src,
                                                   short* __restrict__ dst,
                                                   int R, int C) {
    __shared__ __align__(16) short tile[64 * 65];
    int c0 = blockIdx.x * 64, r0 = blockIdx.y * 64;
    src += (size_t)blockIdx.z * R * C;
    dst += (size_t)blockIdx.z * R * C;
    int tid = threadIdx.x;
#pragma unroll
    for (int it = 0; it < 16; ++it) {
        int idx = it * 256 + tid;
        int rr = idx >> 6, cc = idx & 63;
        tile[cc * 65 + rr] = f2bf(src[(size_t)(r0 + rr) * C + c0 + cc]);
    }
    __syncthreads();
#pragma unroll
    for (int it = 0; it < 16; ++it) {
        int idx = it * 256 + tid;
        int cc = idx >> 6, rr = idx & 63;
        dst[(size_t)(c0 + cc) * R + r0 + rr] = tile[cc * 65 + rr];
    }
}

// ---------------- QKV projection + q/k norm (256-row M-tile) ----------------
// XT: [b][t][d] (d contig, bf16), WT: [nh][e][d] (d contig, bf16)
// Qw (pre-scaled by SCL), Kw: [bh][t][e] ; Vt: [bh][e][t]   (all bf16)
__global__ __launch_bounds__(256, 2) void qkv_k(const short* __restrict__ XT,
                                                const short* __restrict__ WT,
                                                short* __restrict__ Qw,
                                                short* __restrict__ Kw,
                                                short* __restrict__ Vt) {
    __shared__ __align__(16) short ldsA[256 * 72];   // 36864 B
    __shared__ __align__(16) short ldsB[64 * 72];    //  9216 B
    int t0 = blockIdx.x * 256;
    int nh = blockIdx.y;           // n*16 + h
    int b  = blockIdx.z;
    int n = nh >> 4, h = nh & 15;
    int tid = threadIdx.x, wave = tid >> 6, lane = tid & 63;
    int l15 = lane & 15, quad = lane >> 4;

    const short* Arow = XT + ((size_t)b * T_SZ + t0) * DE;
    const short* Brow = WT + (size_t)nh * DH * DE;

    float4v acc[4][4];   // [mm: 16-row subtile of this wave's 64 rows][j: e-subtile]
#pragma unroll
    for (int mm = 0; mm < 4; ++mm)
#pragma unroll
        for (int j = 0; j < 4; ++j) acc[mm][j] = zero4();

    for (int k0 = 0; k0 < DE; k0 += 64) {
        __syncthreads();
#pragma unroll
        for (int it = 0; it < 8; ++it) {       // A: 256x64 = 2048 chunks of 8
            int idx = it * 256 + tid;
            int row = idx >> 3, d8 = (idx & 7) * 8;
            *(short8*)&ldsA[row * 72 + d8] =
                *(const short8*)&Arow[(size_t)row * DE + k0 + d8];
        }
#pragma unroll
        for (int it = 0; it < 2; ++it) {       // B: 64x64 = 512 chunks
            int idx = it * 256 + tid;
            int row = idx >> 3, d8 = (idx & 7) * 8;
            *(short8*)&ldsB[row * 72 + d8] =
                *(const short8*)&Brow[(size_t)row * DE + k0 + d8];
        }
        __syncthreads();
#pragma unroll
        for (int ks = 0; ks < 2; ++ks) {
            short8 af[4], bf[4];
#pragma unroll
            for (int mm = 0; mm < 4; ++mm)
                af[mm] = *(const short8*)&ldsA[(64 * wave + 16 * mm + l15) * 72 + ks * 32 + quad * 8];
#pragma unroll
            for (int j = 0; j < 4; ++j)
                bf[j] = *(const short8*)&ldsB[(16 * j + l15) * 72 + ks * 32 + quad * 8];
#pragma unroll
            for (int mm = 0; mm < 4; ++mm)
#pragma unroll
                for (int j = 0; j < 4; ++j)
                    acc[mm][j] = __builtin_amdgcn_mfma_f32_16x16x32_bf16(af[mm], bf[j], acc[mm][j], 0, 0, 0);
        }
    }

    int bh = b * NHEADS + h;
#pragma unroll
    for (int mm = 0; mm < 4; ++mm) {
        int tbase = t0 + 64 * wave + 16 * mm;
        if (n < 2) {
            float oscale = (n == 0) ? SCL : 1.0f;   // fold attention scale into Q
            float mu[4], inv[4];
#pragma unroll
            for (int r = 0; r < 4; ++r) {
                float s1 = 0.f, s2 = 0.f;
#pragma unroll
                for (int j = 0; j < 4; ++j) { float v = acc[mm][j][r]; s1 += v; s2 += v * v; }
                for (int sh = 1; sh < 16; sh <<= 1) {
                    s1 += __shfl_xor(s1, sh, 64);
                    s2 += __shfl_xor(s2, sh, 64);
                }
                mu[r] = s1 * (1.0f / 64.0f);
                float var = (s2 - 64.0f * mu[r] * mu[r]) * (1.0f / 63.0f);
                var = fmaxf(var, 0.0f);
                inv[r] = oscale / (sqrtf(var) + 1e-5f);
            }
            short* dst = (n == 0 ? Qw : Kw) + (size_t)bh * T_SZ * DH;
#pragma unroll
            for (int r = 0; r < 4; ++r) {
                int t = tbase + quad * 4 + r;
#pragma unroll
                for (int j = 0; j < 4; ++j) {
                    float v = (acc[mm][j][r] - mu[r]) * inv[r];
                    dst[(size_t)t * DH + 16 * j + l15] = f2bf(v);
                }
            }
        } else {
#pragma unroll
            for (int r = 0; r < 4; ++r) {
                int t = tbase + quad * 4 + r;
#pragma unroll
                for (int j = 0; j < 4; ++j) {
                    Vt[((size_t)bh * DH + 16 * j + l15) * T_SZ + t] = f2bf(acc[mm][j][r]);
                }
            }
        }
    }
}

// ---------------- flash attention (register-blocked, 64 q-rows/wave) ---------
// Qw (pre-scaled), Kw: [bh][t][e] ; Vt: [bh][e][t]  (bf16) ; out: fp32 [b][h*64+e][t]
// |q.k*SCL| <= 11.4  -> exp2 never overflows; no max subtraction needed.
__global__ __launch_bounds__(256, 2) void attn_k(const short* __restrict__ Qw,
                                                 const short* __restrict__ Kw,
                                                 const short* __restrict__ Vt,
                                                 float* __restrict__ out) {
    __shared__ __align__(16) char smem[55296];
    short* ldsK = (short*)smem;                 // [s][e]    64x72
    short* ldsV = (short*)(smem + 9216);        // [e][s]    64x72
    short* ldsP = (short*)(smem + 18432);       // per-wave [t][s] 64x72
    float* ldsO = (float*)smem;                 // epilogue alias: 2 x (64x68 fp32)

    int t0 = blockIdx.x * 256;
    int bh = blockIdx.y;
    int b = bh >> 4, h = bh & 15;
    int tid = threadIdx.x, wave = tid >> 6, lane = tid & 63;
    int l15 = lane & 15, quad = lane >> 4;
    int tw = t0 + 64 * wave;                    // this wave's 64 q-rows

    const short* Qp = Qw + (size_t)bh * T_SZ * DH;
    const short* Kp = Kw + (size_t)bh * T_SZ * DH;
    const short* Vp = Vt + (size_t)bh * DH * T_SZ;
    short* Pw = ldsP + wave * 64 * 72;

    short8 qf[4][2];   // B-operand: lane holds Q[t=tw+16tt+l15][e=ks*32+quad*8..+7]
#pragma unroll
    for (int tt = 0; tt < 4; ++tt)
#pragma unroll
        for (int ks = 0; ks < 2; ++ks)
            qf[tt][ks] = *(const short8*)&Qp[(size_t)(tw + 16 * tt + l15) * DH + ks * 32 + quad * 8];

    float lsum[4] = {0.f, 0.f, 0.f, 0.f};
    float4v o[4][4];   // [tt][j: e-subtile]
#pragma unroll
    for (int tt = 0; tt < 4; ++tt)
#pragma unroll
        for (int j = 0; j < 4; ++j) o[tt][j] = zero4();

    for (int s0 = 0; s0 < T_SZ; s0 += 64) {
        __syncthreads();
#pragma unroll
        for (int it = 0; it < 2; ++it) {   // stage K [s][e] and V^T [e][s]
            int idx = it * 256 + tid;
            int row = idx >> 3, c8 = (idx & 7) * 8;
            *(short8*)&ldsK[row * 72 + c8] = *(const short8*)&Kp[(size_t)(s0 + row) * DH + c8];
            *(short8*)&ldsV[row * 72 + c8] = *(const short8*)&Vp[(size_t)row * T_SZ + s0 + c8];
        }
        __syncthreads();

        // S^T = K.Q^T: C[row=s_local][col=t_local]; lane's 4 regs = 4 consecutive s
#pragma unroll
        for (int j = 0; j < 4; ++j) {
            short8 k0 = *(const short8*)&ldsK[(16 * j + l15) * 72 + quad * 8];
            short8 k1 = *(const short8*)&ldsK[(16 * j + l15) * 72 + 32 + quad * 8];
#pragma unroll
            for (int tt = 0; tt < 4; ++tt) {
                float4v z = zero4();
                z = __builtin_amdgcn_mfma_f32_16x16x32_bf16(k0, qf[tt][0], z, 0, 0, 0);
                z = __builtin_amdgcn_mfma_f32_16x16x32_bf16(k1, qf[tt][1], z, 0, 0, 0);
                float p0 = __builtin_amdgcn_exp2f(z[0]);
                float p1 = __builtin_amdgcn_exp2f(z[1]);
                float p2 = __builtin_amdgcn_exp2f(z[2]);
                float p3 = __builtin_amdgcn_exp2f(z[3]);
                lsum[tt] += (p0 + p1) + (p2 + p3);
                uint2v u = { pack_bf2(p0, p1), pack_bf2(p2, p3) };
                // P[t=16tt+l15][s=16j+quad*4 .. +3] — this wave's private region
                *(uint2v*)&Pw[(16 * tt + l15) * 72 + 16 * j + quad * 4] = u;
            }
        }

        // PV: A = P[t][s], B = V^T[e][s] — intra-wave P write->read, no barrier
        short8 pf[4][2];
#pragma unroll
        for (int tt = 0; tt < 4; ++tt) {
            pf[tt][0] = *(const short8*)&Pw[(16 * tt + l15) * 72 + quad * 8];
            pf[tt][1] = *(const short8*)&Pw[(16 * tt + l15) * 72 + 32 + quad * 8];
        }
#pragma unroll
        for (int j = 0; j < 4; ++j) {
            short8 v0 = *(const short8*)&ldsV[(16 * j + l15) * 72 + quad * 8];
            short8 v1 = *(const short8*)&ldsV[(16 * j + l15) * 72 + 32 + quad * 8];
#pragma unroll
            for (int tt = 0; tt < 4; ++tt) {
                o[tt][j] = __builtin_amdgcn_mfma_f32_16x16x32_bf16(pf[tt][0], v0, o[tt][j], 0, 0, 0);
                o[tt][j] = __builtin_amdgcn_mfma_f32_16x16x32_bf16(pf[tt][1], v1, o[tt][j], 0, 0, 0);
            }
        }
    }

    // l reduction: lane holds partials for t = tw + 16tt + l15 (quarter per quad)
    float4v rinv[4];
#pragma unroll
    for (int tt = 0; tt < 4; ++tt) {
        lsum[tt] += __shfl_xor(lsum[tt], 16, 64);
        lsum[tt] += __shfl_xor(lsum[tt], 32, 64);
#pragma unroll
        for (int r = 0; r < 4; ++r)
            rinv[tt][r] = 1.0f / __shfl(lsum[tt], quad * 4 + r, 16);  // t = tw+16tt+quad*4+r
    }

    // epilogue: normalize, transpose via LDS (2 phases x 2 waves), float4 stores
#pragma unroll
    for (int ph = 0; ph < 2; ++ph) {
        __syncthreads();
        if ((wave >> 1) == ph) {
            float* Ow = ldsO + (wave & 1) * (64 * 68);
#pragma unroll
            for (int tt = 0; tt < 4; ++tt)
#pragma unroll
                for (int j = 0; j < 4; ++j) {
                    float4v ov = o[tt][j] * rinv[tt];
                    // O[t = tw+16tt+quad*4+r][e = 16j+l15]
                    *(float4v*)&Ow[(16 * j + l15) * 68 + 16 * tt + quad * 4] = ov;
                }
        }
        __syncthreads();
#pragma unroll
        for (int it = 0; it < 8; ++it) {
            int idx = it * 256 + tid;          // 2048 float4 = 2 regions x 64e x 64t
            int reg = idx >> 10;
            int rid = idx & 1023;
            int e = rid >> 4, t4 = (rid & 15) * 4;
            *(float4v*)&out[((size_t)(b * DE + h * DH + e)) * T_SZ + t0 + 128 * ph + 64 * reg + t4] =
                *(const float4v*)&ldsO[reg * (64 * 68) + e * 68 + t4];
        }
    }
}

extern "C" void kernel_launch(void* const* d_in, const int* in_sizes, int n_in,
                              void* d_out, int out_size, void* d_ws, size_t ws_size,
                              hipStream_t stream) {
    const float* x = (const float*)d_in[0];   // fp32 [B][D][T]
    const float* w = (const float*)d_in[1];   // fp32 [3][H][D][dh]
    float* out = (float*)d_out;               // fp32 [B][D][T]
    char* ws = (char*)d_ws;

    const size_t XT_BYTES = (size_t)B_SZ * T_SZ * DE * 2;       // 16.8 MB (bf16)
    const size_t WT_BYTES = (size_t)3 * NHEADS * DH * DE * 2;   // 6.3 MB
    const size_t QKV_BYTES = (size_t)BH * T_SZ * DH * 2;        // 16.8 MB each

    short* XT = (short*)(ws);
    short* WT = (short*)(ws + XT_BYTES);
    short* Qw = (short*)(ws + XT_BYTES + WT_BYTES);
    short* Kw = (short*)(ws + XT_BYTES + WT_BYTES + QKV_BYTES);
    short* Vt = (short*)(ws + XT_BYTES + WT_BYTES + 2 * QKV_BYTES);

    // x: per-b fp32 [D][T] -> bf16 XT [T][D]
    transpose_k<<<dim3(T_SZ / 64, DE / 64, B_SZ), 256, 0, stream>>>(x, XT, DE, T_SZ);
    // w: per-nh fp32 [D][dh] -> bf16 WT [dh][D]
    transpose_k<<<dim3(1, DE / 64, 3 * NHEADS), 256, 0, stream>>>(w, WT, DE, DH);
    qkv_k<<<dim3(T_SZ / 256, 3 * NHEADS, B_SZ), 256, 0, stream>>>(XT, WT, Qw, Kw, Vt);
    attn_k<<<dim3(T_SZ / 256, BH), 256, 0, stream>>>(Qw, Kw, Vt, out);
}